// Round 9
// baseline (1200.330 us; speedup 1.0000x reference)
//
#include <hip/hip_runtime.h>
#include <hip/hip_fp16.h>
#include <math.h>

#define N_B 16
#define N_A 1024
#define N_D 1024
#define N_H 512
#define N_W 512

typedef _Float16 half2t __attribute__((ext_vector_type(2)));
typedef unsigned uint4v __attribute__((ext_vector_type(4)));

__device__ inline half2t h2cast(unsigned u) {
    union { unsigned u; half2t h; } cv; cv.u = u; return cv.h;
}

__device__ inline float fdot2f(half2t a, half2t b, float c) {
#if __has_builtin(__builtin_amdgcn_fdot2)
    return __builtin_amdgcn_fdot2(a, b, c, false);
#else
    asm("v_dot2_f32_f16 %0, %1, %2, %0" : "+v"(c) : "v"(a), "v"(b));
    return c;
#endif
}

__device__ inline half2t pack_h2(float lo, float hi) {
#if __has_builtin(__builtin_amdgcn_cvt_pkrtz)
    auto r = __builtin_amdgcn_cvt_pkrtz(lo, hi);
    union { decltype(r) a; half2t h; } cv; cv.a = r; return cv.h;
#else
    half2t r; r.x = (_Float16)lo; r.y = (_Float16)hi; return r;
#endif
}

__device__ inline unsigned pack_u(float lo, float hi) {
    union { half2t h; unsigned u; } cv; cv.h = pack_h2(lo, hi); return cv.u;
}

__device__ inline float med3f(float a, float lo, float hi) {
#if __has_builtin(__builtin_amdgcn_fmed3f)
    return __builtin_amdgcn_fmed3f(a, lo, hi);
#else
    return fminf(fmaxf(a, lo), hi);
#endif
}

// ---------------------------------------------------------------------------
__global__ void fan_setup_kernel(const float* __restrict__ angles,
                                 float* __restrict__ twr,
                                 float* __restrict__ twi,
                                 float2* __restrict__ cs) {
    int t = blockIdx.x * 256 + threadIdx.x;
    if (t < 512) {
        double ang = -2.0 * M_PI * (double)t / 1024.0;
        twr[t] = (float)cos(ang);
        twi[t] = (float)sin(ang);
    }
    if (t < 1024) {
        double b = (double)angles[t];
        cs[t] = make_float2((float)cos(b), (float)sin(b));
    }
}

// ---------------------------------------------------------------------------
// FFT ramp filter, 4 batch-rows per block (one angle), as TWO packed complex
// FFTs. INTERLEAVED output: entry (a,d) is 64 B = 4 group-chunks of 16 B at
// byte (a*1024+d)*64 + g*16. Backprojection reads all 64 B from ONE base
// with offset:0/16/32/48 -> single memory stream.
// ---------------------------------------------------------------------------
__global__ __launch_bounds__(256) void fan_fft_filter4_kernel(
    const float* __restrict__ sino, const float* __restrict__ filt,
    const float* __restrict__ twr_g, const float* __restrict__ twi_g,
    uint4* __restrict__ pf4) {
    __shared__ float s_re0[1024], s_im0[1024];
    __shared__ float s_re1[1024], s_im1[1024];
    __shared__ float s_twr[512], s_twi[512];

    const int tid = threadIdx.x;
    const int a = blockIdx.x & (N_A - 1);
    const int g = blockIdx.x >> 10;

    {
        float2 t0 = ((const float2*)twr_g)[tid];
        s_twr[2 * tid] = t0.x; s_twr[2 * tid + 1] = t0.y;
        float2 t1 = ((const float2*)twi_g)[tid];
        s_twi[2 * tid] = t1.x; s_twi[2 * tid + 1] = t1.y;
    }
    {
        const size_t rowstride = (size_t)N_A * N_D;
        const float* rb = sino + (size_t)(4 * g) * rowstride + (size_t)a * N_D;
        ((float4*)s_re0)[tid] = ((const float4*)(rb + 0 * rowstride))[tid];
        ((float4*)s_im0)[tid] = ((const float4*)(rb + 1 * rowstride))[tid];
        ((float4*)s_re1)[tid] = ((const float4*)(rb + 2 * rowstride))[tid];
        ((float4*)s_im1)[tid] = ((const float4*)(rb + 3 * rowstride))[tid];
    }
    __syncthreads();

    for (int L = 9; L >= 0; --L) {
        const int half = 1 << L;
#pragma unroll
        for (int q = 0; q < 4; ++q) {
            float* re = (q < 2) ? s_re0 : s_re1;
            float* im = (q < 2) ? s_im0 : s_im1;
            const int bf = tid + ((q & 1) << 8);
            const int j = bf & (half - 1);
            const int blk = bf >> L;
            const int base = (blk << (L + 1)) + j;
            const int tw = j << (9 - L);
            const float wr = s_twr[tw], wi = s_twi[tw];
            const float ar = re[base], ai = im[base];
            const float br = re[base + half], bi = im[base + half];
            re[base] = ar + br;
            im[base] = ai + bi;
            const float dr = ar - br, di = ai - bi;
            re[base + half] = dr * wr - di * wi;
            im[base + half] = dr * wi + di * wr;
        }
        __syncthreads();
    }

#pragma unroll
    for (int q = 0; q < 4; ++q) {
        const int i = tid + (q << 8);
        const int ri = (int)(__brev((unsigned)i) >> 22);
        const float f = filt[ri];
        s_re0[i] *= f; s_im0[i] *= f;
        s_re1[i] *= f; s_im1[i] *= f;
    }
    __syncthreads();

    for (int L = 0; L <= 9; ++L) {
        const int half = 1 << L;
#pragma unroll
        for (int q = 0; q < 4; ++q) {
            float* re = (q < 2) ? s_re0 : s_re1;
            float* im = (q < 2) ? s_im0 : s_im1;
            const int bf = tid + ((q & 1) << 8);
            const int j = bf & (half - 1);
            const int blk = bf >> L;
            const int base = (blk << (L + 1)) + j;
            const int tw = j << (9 - L);
            const float wr = s_twr[tw], wi = -s_twi[tw];
            const float ar = re[base], ai = im[base];
            const float tr = re[base + half], ti = im[base + half];
            const float br = tr * wr - ti * wi;
            const float bi = tr * wi + ti * wr;
            re[base] = ar + br;
            im[base] = ai + bi;
            re[base + half] = ar - br;
            im[base + half] = ai - bi;
        }
        __syncthreads();
    }

    const float invN = 1.0f / 1024.0f;
    // interleaved: uint4 index = a*4096 + d*4 + g
    uint4* dst = pf4 + ((size_t)a * 4096 + (size_t)g);
#pragma unroll
    for (int q = 0; q < 4; ++q) {
        const int n = tid + (q << 8);
        const int n1 = (n < 1023) ? n + 1 : n;
        const float e = (n < 1023) ? 1.0f : 0.0f;
        uint4 v;
        v.x = pack_u(s_re0[n] * invN, s_re0[n1] * invN * e);
        v.y = pack_u(s_im0[n] * invN, s_im0[n1] * invN * e);
        v.z = pack_u(s_re1[n] * invN, s_re1[n1] * invN * e);
        v.w = pack_u(s_im1[n] * invN, s_im1[n1] * invN * e);
        dst[(size_t)n * 4] = v;
    }
}

// ---------------------------------------------------------------------------
// Backprojection: 16x16 pixel tile per block. Depth-3 single-angle register
// banks (A/B/C), inline-asm single-base gathers (offset:0/16/32/48), counted
// s_waitcnt vmcnt(8). SPLIT=8 maps part = blockIdx&7 -> one angle slice per
// XCD (round-robin dispatch) so each XCD's L2 works on its 8 MB slice.
// ---------------------------------------------------------------------------
#define GEOM(A_, WP_, OFF_)                                                   \
    {                                                                         \
        const int a_ = (A_);                                                  \
        const float2 csp = lcs[a_];                                           \
        const float c = csp.x, s = csp.y;                                     \
        const float t = fmaf(x, c, fmaf(y, s, 750.0f));                       \
        const float r = __builtin_amdgcn_rcpf(t);                             \
        const float num = fmaf(y, c, -(x * s));                               \
        const float idx = fmaf(num * r, 960.0f, 511.5f);                      \
        const float idxc = med3f(idx, 0.0f, 1023.0f);                         \
        const float i0f = floorf(idxc);                                       \
        const float frac = idxc - i0f;                                        \
        const float wr_ = 750.0f * r;                                         \
        float wd = wr_ * wr_;                                                 \
        wd = (idx == idxc) ? wd : 0.0f;                                       \
        const float w1 = wd * frac;                                           \
        const float w0 = wd - w1;                                             \
        WP_ = pack_h2(w0, w1);                                                \
        OFF_ = (((unsigned)a_ << 10) + (unsigned)(int)i0f) << 6;              \
    }

// 4 loads from ONE SGPR-pair base, shared 32-bit byte voffset, imm offsets.
#define ISSUE4(V0_, V1_, V2_, V3_, OFF_)                                      \
    asm volatile(                                                             \
        "global_load_dwordx4 %0, %4, %5\n\t"                                  \
        "global_load_dwordx4 %1, %4, %5 offset:16\n\t"                        \
        "global_load_dwordx4 %2, %4, %5 offset:32\n\t"                        \
        "global_load_dwordx4 %3, %4, %5 offset:48"                            \
        : "=&v"(V0_), "=&v"(V1_), "=&v"(V2_), "=&v"(V3_)                      \
        : "v"(OFF_), "s"(gB));

#define VMWAIT(N_)                                                            \
    {                                                                         \
        asm volatile("s_waitcnt vmcnt(" #N_ ")" ::: "memory");                \
        __builtin_amdgcn_sched_barrier(0);                                    \
    }

#define CONSUME(WP_, V0_, V1_, V2_, V3_)                                      \
    {                                                                         \
        acc[0] = fdot2f(h2cast(V0_[0]), WP_, acc[0]);                         \
        acc[1] = fdot2f(h2cast(V0_[1]), WP_, acc[1]);                         \
        acc[2] = fdot2f(h2cast(V0_[2]), WP_, acc[2]);                         \
        acc[3] = fdot2f(h2cast(V0_[3]), WP_, acc[3]);                         \
        acc[4] = fdot2f(h2cast(V1_[0]), WP_, acc[4]);                         \
        acc[5] = fdot2f(h2cast(V1_[1]), WP_, acc[5]);                         \
        acc[6] = fdot2f(h2cast(V1_[2]), WP_, acc[6]);                         \
        acc[7] = fdot2f(h2cast(V1_[3]), WP_, acc[7]);                         \
        acc[8] = fdot2f(h2cast(V2_[0]), WP_, acc[8]);                         \
        acc[9] = fdot2f(h2cast(V2_[1]), WP_, acc[9]);                         \
        acc[10] = fdot2f(h2cast(V2_[2]), WP_, acc[10]);                       \
        acc[11] = fdot2f(h2cast(V2_[3]), WP_, acc[11]);                       \
        acc[12] = fdot2f(h2cast(V3_[0]), WP_, acc[12]);                       \
        acc[13] = fdot2f(h2cast(V3_[1]), WP_, acc[13]);                       \
        acc[14] = fdot2f(h2cast(V3_[2]), WP_, acc[14]);                       \
        acc[15] = fdot2f(h2cast(V3_[3]), WP_, acc[15]);                       \
    }

#define ISSUE_ONE(X, AA)                                                      \
    {                                                                         \
        unsigned off_;                                                        \
        GEOM((AA), wp##X, off_);                                              \
        ISSUE4(X##0, X##1, X##2, X##3, off_);                                 \
    }

// body: issue angle AA into bank T, wait, consume bank S (issued 2 ago)
#define BODY(T, S, AA)                                                        \
    {                                                                         \
        ISSUE_ONE(T, (AA));                                                   \
        VMWAIT(8);                                                            \
        CONSUME(wp##S, S##0, S##1, S##2, S##3);                               \
    }

template <int SPLIT>
__global__ __launch_bounds__(256, 4) void fan_backproject_kernel(
    const uint4* __restrict__ pf4, const float2* __restrict__ cs_g,
    float* __restrict__ dst0) {
    __shared__ float2 lcs[N_A];
    const int tid = threadIdx.x;
#pragma unroll
    for (int q = 0; q < 4; ++q) {
        const int a = tid + (q << 8);
        lcs[a] = cs_g[a];
    }
    __syncthreads();

    int part, tb;
    if (SPLIT == 8) {
        part = blockIdx.x & 7;       // round-robin dispatch -> part per XCD
        tb = blockIdx.x >> 3;
    } else if (SPLIT == 2) {
        const unsigned nwg = gridDim.x;
        const unsigned swz = (blockIdx.x & 7) * (nwg >> 3) + (blockIdx.x >> 3);
        part = (int)(swz >> 10);
        tb = (int)(swz & 1023);
    } else {
        part = 0;
        tb = blockIdx.x;
    }
    const int ACNT = N_A / SPLIT;
    const int abase = part * ACNT;

    // 16x16 tile: 32x32 grid of tiles
    const int tile_x = tb & 31;
    const int tile_y = tb >> 5;
    const int tx = tid & 15;
    const int ty = tid >> 4;
    const int xi = tile_x * 16 + tx;
    const int yi = tile_y * 16 + ty;
    const float x = ((float)xi - 255.5f);  // VX = 1.0
    const float y = ((float)yi - 255.5f);

    const unsigned* gB = (const unsigned*)pf4;  // single base (SGPR pair)

    float acc[N_B];
#pragma unroll
    for (int b = 0; b < N_B; ++b) acc[b] = 0.0f;

    half2t wpA, wpB, wpC;
    uint4v A0, A1, A2, A3, B0, B1, B2, B3, C0, C1, C2, C3;

    // prologue: angles 0,1 into banks A,B
    ISSUE_ONE(A, abase + 0);
    ISSUE_ONE(B, abase + 1);
    // main: n = 2..ACNT-1, bank(n) = n%3.  (ACNT-2) divisible by 3 for
    // ACNT in {128, 512} (both ≡ 2 mod 3).
    int aa = abase + 2;
    for (int it = 0; it < (ACNT - 2) / 3; ++it) {
        BODY(C, A, aa);
        BODY(A, B, aa + 1);
        BODY(B, C, aa + 2);
        aa += 3;
    }
    // epilogue: un-consumed banks A (n=ACNT-2) and B (n=ACNT-1)
    VMWAIT(4);
    CONSUME(wpA, A0, A1, A2, A3);
    VMWAIT(0);
    CONSUME(wpB, B0, B1, B2, B3);

    const float scale = 3.14159265358979323846f / 1024.0f;  // pi / A
    float* dst = dst0 + (size_t)part * ((size_t)N_B * N_H * N_W);
    const size_t pix = (size_t)yi * N_W + (size_t)xi;
#pragma unroll
    for (int b = 0; b < N_B; ++b) {
        dst[(size_t)b * (N_H * N_W) + pix] = acc[b] * scale;
    }
}

// ---------------------------------------------------------------------------
template <int NS>
__global__ __launch_bounds__(256) void fan_reduce_kernel(
    const float4* __restrict__ p, float4* __restrict__ o) {
    const int i = blockIdx.x * 256 + threadIdx.x;
    const size_t stride = (size_t)N_B * N_H * N_W / 4;
    float4 v = p[i];
#pragma unroll
    for (int k = 1; k < NS; ++k) {
        const float4 w = p[(size_t)k * stride + i];
        v.x += w.x; v.y += w.y; v.z += w.z; v.w += w.w;
    }
    o[i] = v;
}

// ---------------------------------------------------------------------------
extern "C" void kernel_launch(void* const* d_in, const int* in_sizes, int n_in,
                              void* d_out, int out_size, void* d_ws, size_t ws_size,
                              hipStream_t stream) {
    const float* sino = (const float*)d_in[0];    // [16, 1024, 1024] f32
    const float* filt = (const float*)d_in[1];    // [1024] f32
    const float* angles = (const float*)d_in[2];  // [1024] f32
    float* out = (float*)d_out;                   // [16, 512, 512] f32

    float* twr = (float*)d_ws;
    float* twi = twr + 512;
    float2* cs = (float2*)(twi + 512);
    char* base = (char*)d_ws;
    uint4* pf4 = (uint4*)(base + 16384);
    const size_t PF_BYTES = (size_t)N_A * N_D * 64;        // 64 MB
    float* partials = (float*)(base + 16384 + PF_BYTES);
    const size_t PART = (size_t)N_B * N_H * N_W;           // 4M floats
    const size_t need8 = 16384 + PF_BYTES + 8 * PART * 4;  // ~192 MB
    const size_t need2 = 16384 + PF_BYTES + 2 * PART * 4;  // ~96 MB

    fan_setup_kernel<<<4, 256, 0, stream>>>(angles, twr, twi, cs);
    fan_fft_filter4_kernel<<<4 * N_A, 256, 0, stream>>>(sino, filt, twr, twi,
                                                        pf4);
    if (ws_size >= need8) {
        fan_backproject_kernel<8><<<1024 * 8, 256, 0, stream>>>(pf4, cs,
                                                                partials);
        fan_reduce_kernel<8><<<(int)(PART / 4 / 256), 256, 0, stream>>>(
            (const float4*)partials, (float4*)out);
    } else if (ws_size >= need2) {
        fan_backproject_kernel<2><<<1024 * 2, 256, 0, stream>>>(pf4, cs,
                                                                partials);
        fan_reduce_kernel<2><<<(int)(PART / 4 / 256), 256, 0, stream>>>(
            (const float4*)partials, (float4*)out);
    } else {
        fan_backproject_kernel<1><<<1024, 256, 0, stream>>>(pf4, cs, out);
    }
}

// Round 10
// 573.223 us; speedup vs baseline: 2.0940x; 2.0940x over previous
//
#include <hip/hip_runtime.h>
#include <hip/hip_fp16.h>
#include <math.h>

#define N_B 16
#define N_A 1024
#define N_D 1024
#define N_H 512
#define N_W 512

typedef _Float16 half2t __attribute__((ext_vector_type(2)));
typedef unsigned uint4v __attribute__((ext_vector_type(4)));

__device__ inline half2t h2cast(unsigned u) {
    union { unsigned u; half2t h; } cv; cv.u = u; return cv.h;
}

__device__ inline float fdot2f(half2t a, half2t b, float c) {
#if __has_builtin(__builtin_amdgcn_fdot2)
    return __builtin_amdgcn_fdot2(a, b, c, false);
#else
    asm("v_dot2_f32_f16 %0, %1, %2, %0" : "+v"(c) : "v"(a), "v"(b));
    return c;
#endif
}

__device__ inline half2t pack_h2(float lo, float hi) {
#if __has_builtin(__builtin_amdgcn_cvt_pkrtz)
    auto r = __builtin_amdgcn_cvt_pkrtz(lo, hi);
    union { decltype(r) a; half2t h; } cv; cv.a = r; return cv.h;
#else
    half2t r; r.x = (_Float16)lo; r.y = (_Float16)hi; return r;
#endif
}

__device__ inline unsigned pack_u(float lo, float hi) {
    union { half2t h; unsigned u; } cv; cv.h = pack_h2(lo, hi); return cv.u;
}

__device__ inline float med3f(float a, float lo, float hi) {
#if __has_builtin(__builtin_amdgcn_fmed3f)
    return __builtin_amdgcn_fmed3f(a, lo, hi);
#else
    return fminf(fmaxf(a, lo), hi);
#endif
}

// ---------------------------------------------------------------------------
__global__ void fan_setup_kernel(const float* __restrict__ angles,
                                 float* __restrict__ twr,
                                 float* __restrict__ twi,
                                 float2* __restrict__ cs) {
    int t = blockIdx.x * 256 + threadIdx.x;
    if (t < 512) {
        double ang = -2.0 * M_PI * (double)t / 1024.0;
        twr[t] = (float)cos(ang);
        twi[t] = (float)sin(ang);
    }
    if (t < 1024) {
        double b = (double)angles[t];
        cs[t] = make_float2((float)cos(b), (float)sin(b));
    }
}

// ---------------------------------------------------------------------------
// FFT ramp filter, 4 batch-rows per block (one angle), as TWO packed complex
// FFTs. Output layout [g][a][d] (16B entries, 16B lane stride in d):
// pf4[(g*1024 + a)*1024 + d] = 4 batches' bilinear half2 pair (f[d], f[d+1]).
// ---------------------------------------------------------------------------
__global__ __launch_bounds__(256) void fan_fft_filter4_kernel(
    const float* __restrict__ sino, const float* __restrict__ filt,
    const float* __restrict__ twr_g, const float* __restrict__ twi_g,
    uint4* __restrict__ pf4) {
    __shared__ float s_re0[1024], s_im0[1024];
    __shared__ float s_re1[1024], s_im1[1024];
    __shared__ float s_twr[512], s_twi[512];

    const int tid = threadIdx.x;
    const int a = blockIdx.x & (N_A - 1);
    const int g = blockIdx.x >> 10;

    {
        float2 t0 = ((const float2*)twr_g)[tid];
        s_twr[2 * tid] = t0.x; s_twr[2 * tid + 1] = t0.y;
        float2 t1 = ((const float2*)twi_g)[tid];
        s_twi[2 * tid] = t1.x; s_twi[2 * tid + 1] = t1.y;
    }
    {
        const size_t rowstride = (size_t)N_A * N_D;
        const float* rb = sino + (size_t)(4 * g) * rowstride + (size_t)a * N_D;
        ((float4*)s_re0)[tid] = ((const float4*)(rb + 0 * rowstride))[tid];
        ((float4*)s_im0)[tid] = ((const float4*)(rb + 1 * rowstride))[tid];
        ((float4*)s_re1)[tid] = ((const float4*)(rb + 2 * rowstride))[tid];
        ((float4*)s_im1)[tid] = ((const float4*)(rb + 3 * rowstride))[tid];
    }
    __syncthreads();

    for (int L = 9; L >= 0; --L) {
        const int half = 1 << L;
#pragma unroll
        for (int q = 0; q < 4; ++q) {
            float* re = (q < 2) ? s_re0 : s_re1;
            float* im = (q < 2) ? s_im0 : s_im1;
            const int bf = tid + ((q & 1) << 8);
            const int j = bf & (half - 1);
            const int blk = bf >> L;
            const int base = (blk << (L + 1)) + j;
            const int tw = j << (9 - L);
            const float wr = s_twr[tw], wi = s_twi[tw];
            const float ar = re[base], ai = im[base];
            const float br = re[base + half], bi = im[base + half];
            re[base] = ar + br;
            im[base] = ai + bi;
            const float dr = ar - br, di = ai - bi;
            re[base + half] = dr * wr - di * wi;
            im[base + half] = dr * wi + di * wr;
        }
        __syncthreads();
    }

#pragma unroll
    for (int q = 0; q < 4; ++q) {
        const int i = tid + (q << 8);
        const int ri = (int)(__brev((unsigned)i) >> 22);
        const float f = filt[ri];
        s_re0[i] *= f; s_im0[i] *= f;
        s_re1[i] *= f; s_im1[i] *= f;
    }
    __syncthreads();

    for (int L = 0; L <= 9; ++L) {
        const int half = 1 << L;
#pragma unroll
        for (int q = 0; q < 4; ++q) {
            float* re = (q < 2) ? s_re0 : s_re1;
            float* im = (q < 2) ? s_im0 : s_im1;
            const int bf = tid + ((q & 1) << 8);
            const int j = bf & (half - 1);
            const int blk = bf >> L;
            const int base = (blk << (L + 1)) + j;
            const int tw = j << (9 - L);
            const float wr = s_twr[tw], wi = -s_twi[tw];
            const float ar = re[base], ai = im[base];
            const float tr = re[base + half], ti = im[base + half];
            const float br = tr * wr - ti * wi;
            const float bi = tr * wi + ti * wr;
            re[base] = ar + br;
            im[base] = ai + bi;
            re[base + half] = ar - br;
            im[base + half] = ai - bi;
        }
        __syncthreads();
    }

    const float invN = 1.0f / 1024.0f;
    uint4* dst = pf4 + ((size_t)g * N_A + (size_t)a) * N_D;
#pragma unroll
    for (int q = 0; q < 4; ++q) {
        const int n = tid + (q << 8);
        const int n1 = (n < 1023) ? n + 1 : n;
        const float e = (n < 1023) ? 1.0f : 0.0f;
        uint4 v;
        v.x = pack_u(s_re0[n] * invN, s_re0[n1] * invN * e);
        v.y = pack_u(s_im0[n] * invN, s_im0[n1] * invN * e);
        v.z = pack_u(s_re1[n] * invN, s_re1[n1] * invN * e);
        v.w = pack_u(s_im1[n] * invN, s_im1[n1] * invN * e);
        dst[n] = v;
    }
}

// ---------------------------------------------------------------------------
// Backprojection: 16x16 pixel tile per block. [g][a][d] layout (16B lane
// stride). Inline-asm saddr gathers (4 bases, shared voffset), depth-3
// single-angle register banks, counted s_waitcnt vmcnt(8). SPLIT=8:
// part = blockIdx&7 -> round-robin dispatch pins one 8MB angle slice per XCD.
// ---------------------------------------------------------------------------
#define GEOM(A_, WP_, OFF_)                                                   \
    {                                                                         \
        const int a_ = (A_);                                                  \
        const float2 csp = lcs[a_];                                           \
        const float c = csp.x, s = csp.y;                                     \
        const float t = fmaf(x, c, fmaf(y, s, 750.0f));                       \
        const float r = __builtin_amdgcn_rcpf(t);                             \
        const float num = fmaf(y, c, -(x * s));                               \
        const float idx = fmaf(num * r, 960.0f, 511.5f);                      \
        const float idxc = med3f(idx, 0.0f, 1023.0f);                         \
        const float i0f = floorf(idxc);                                       \
        const float frac = idxc - i0f;                                        \
        const float wr_ = 750.0f * r;                                         \
        float wd = wr_ * wr_;                                                 \
        wd = (idx == idxc) ? wd : 0.0f;                                       \
        const float w1 = wd * frac;                                           \
        const float w0 = wd - w1;                                             \
        WP_ = pack_h2(w0, w1);                                                \
        OFF_ = (((unsigned)a_ << 10) + (unsigned)(int)i0f) << 4;              \
    }

// 4 loads: 4 SGPR-pair bases, one shared 32-bit byte voffset. Early-clobber.
#define ISSUE4(V0_, V1_, V2_, V3_, OFF_)                                      \
    asm volatile(                                                             \
        "global_load_dwordx4 %0, %4, %5\n\t"                                  \
        "global_load_dwordx4 %1, %4, %6\n\t"                                  \
        "global_load_dwordx4 %2, %4, %7\n\t"                                  \
        "global_load_dwordx4 %3, %4, %8"                                      \
        : "=&v"(V0_), "=&v"(V1_), "=&v"(V2_), "=&v"(V3_)                      \
        : "v"(OFF_), "s"(g0), "s"(g1), "s"(g2), "s"(g3));

#define VMWAIT(N_)                                                            \
    {                                                                         \
        asm volatile("s_waitcnt vmcnt(" #N_ ")" ::: "memory");                \
        __builtin_amdgcn_sched_barrier(0);                                    \
    }

#define CONSUME(WP_, V0_, V1_, V2_, V3_)                                      \
    {                                                                         \
        acc[0] = fdot2f(h2cast(V0_[0]), WP_, acc[0]);                         \
        acc[1] = fdot2f(h2cast(V0_[1]), WP_, acc[1]);                         \
        acc[2] = fdot2f(h2cast(V0_[2]), WP_, acc[2]);                         \
        acc[3] = fdot2f(h2cast(V0_[3]), WP_, acc[3]);                         \
        acc[4] = fdot2f(h2cast(V1_[0]), WP_, acc[4]);                         \
        acc[5] = fdot2f(h2cast(V1_[1]), WP_, acc[5]);                         \
        acc[6] = fdot2f(h2cast(V1_[2]), WP_, acc[6]);                         \
        acc[7] = fdot2f(h2cast(V1_[3]), WP_, acc[7]);                         \
        acc[8] = fdot2f(h2cast(V2_[0]), WP_, acc[8]);                         \
        acc[9] = fdot2f(h2cast(V2_[1]), WP_, acc[9]);                         \
        acc[10] = fdot2f(h2cast(V2_[2]), WP_, acc[10]);                       \
        acc[11] = fdot2f(h2cast(V2_[3]), WP_, acc[11]);                       \
        acc[12] = fdot2f(h2cast(V3_[0]), WP_, acc[12]);                       \
        acc[13] = fdot2f(h2cast(V3_[1]), WP_, acc[13]);                       \
        acc[14] = fdot2f(h2cast(V3_[2]), WP_, acc[14]);                       \
        acc[15] = fdot2f(h2cast(V3_[3]), WP_, acc[15]);                       \
    }

#define ISSUE_ONE(X, AA)                                                      \
    {                                                                         \
        unsigned off_;                                                        \
        GEOM((AA), wp##X, off_);                                              \
        ISSUE4(X##0, X##1, X##2, X##3, off_);                                 \
    }

// body: issue angle AA into bank T, wait (2 banks in flight), consume bank S
#define BODY(T, S, AA)                                                        \
    {                                                                         \
        ISSUE_ONE(T, (AA));                                                   \
        VMWAIT(8);                                                            \
        CONSUME(wp##S, S##0, S##1, S##2, S##3);                               \
    }

template <int SPLIT>
__global__ __launch_bounds__(256, 4) void fan_backproject_kernel(
    const uint4* __restrict__ pf4, const float2* __restrict__ cs_g,
    float* __restrict__ dst0) {
    __shared__ float2 lcs[N_A];
    const int tid = threadIdx.x;
#pragma unroll
    for (int q = 0; q < 4; ++q) {
        const int a = tid + (q << 8);
        lcs[a] = cs_g[a];
    }
    __syncthreads();

    int part, tb;
    if (SPLIT == 8) {
        part = blockIdx.x & 7;       // round-robin dispatch -> slice per XCD
        tb = blockIdx.x >> 3;
    } else if (SPLIT == 2) {
        const unsigned nwg = gridDim.x;
        const unsigned swz = (blockIdx.x & 7) * (nwg >> 3) + (blockIdx.x >> 3);
        part = (int)(swz >> 10);
        tb = (int)(swz & 1023);
    } else {
        part = 0;
        tb = blockIdx.x;
    }
    const int ACNT = N_A / SPLIT;
    const int abase = part * ACNT;

    // 16x16 tile: 32x32 grid of tiles
    const int tile_x = tb & 31;
    const int tile_y = tb >> 5;
    const int tx = tid & 15;
    const int ty = tid >> 4;
    const int xi = tile_x * 16 + tx;
    const int yi = tile_y * 16 + ty;
    const float x = ((float)xi - 255.5f);  // VX = 1.0
    const float y = ((float)yi - 255.5f);

    // 4 uniform group bases (SGPR pairs for the asm saddr form)
    const unsigned* g0 = (const unsigned*)pf4;
    const unsigned* g1 = g0 + ((size_t)1 << 22);  // +16 MB in dwords
    const unsigned* g2 = g0 + ((size_t)2 << 22);
    const unsigned* g3 = g0 + ((size_t)3 << 22);

    float acc[N_B];
#pragma unroll
    for (int b = 0; b < N_B; ++b) acc[b] = 0.0f;

    half2t wpA, wpB, wpC;
    uint4v A0, A1, A2, A3, B0, B1, B2, B3, C0, C1, C2, C3;

    // prologue: angles 0,1 into banks A,B
    ISSUE_ONE(A, abase + 0);
    ISSUE_ONE(B, abase + 1);
    int aa = abase + 2;
    for (int it = 0; it < (ACNT - 2) / 3; ++it) {
        BODY(C, A, aa);
        BODY(A, B, aa + 1);
        BODY(B, C, aa + 2);
        aa += 3;
    }
    if ((ACNT - 2) % 3 == 2) {  // ACNT = 1024 tail
        BODY(C, A, aa);
        BODY(A, B, aa + 1);
        VMWAIT(4);
        CONSUME(wpC, C0, C1, C2, C3);
        VMWAIT(0);
        CONSUME(wpA, A0, A1, A2, A3);
    } else {                    // ACNT = 128 / 512
        VMWAIT(4);
        CONSUME(wpA, A0, A1, A2, A3);
        VMWAIT(0);
        CONSUME(wpB, B0, B1, B2, B3);
    }

    const float scale = 3.14159265358979323846f / 1024.0f;  // pi / A
    float* dst = dst0 + (size_t)part * ((size_t)N_B * N_H * N_W);
    const size_t pix = (size_t)yi * N_W + (size_t)xi;
#pragma unroll
    for (int b = 0; b < N_B; ++b) {
        dst[(size_t)b * (N_H * N_W) + pix] = acc[b] * scale;
    }
}

// ---------------------------------------------------------------------------
template <int NS>
__global__ __launch_bounds__(256) void fan_reduce_kernel(
    const float4* __restrict__ p, float4* __restrict__ o) {
    const int i = blockIdx.x * 256 + threadIdx.x;
    const size_t stride = (size_t)N_B * N_H * N_W / 4;
    float4 v = p[i];
#pragma unroll
    for (int k = 1; k < NS; ++k) {
        const float4 w = p[(size_t)k * stride + i];
        v.x += w.x; v.y += w.y; v.z += w.z; v.w += w.w;
    }
    o[i] = v;
}

// ---------------------------------------------------------------------------
extern "C" void kernel_launch(void* const* d_in, const int* in_sizes, int n_in,
                              void* d_out, int out_size, void* d_ws, size_t ws_size,
                              hipStream_t stream) {
    const float* sino = (const float*)d_in[0];    // [16, 1024, 1024] f32
    const float* filt = (const float*)d_in[1];    // [1024] f32
    const float* angles = (const float*)d_in[2];  // [1024] f32
    float* out = (float*)d_out;                   // [16, 512, 512] f32

    float* twr = (float*)d_ws;
    float* twi = twr + 512;
    float2* cs = (float2*)(twi + 512);
    char* base = (char*)d_ws;
    uint4* pf4 = (uint4*)(base + 16384);
    const size_t PF_BYTES = (size_t)4 * N_A * N_D * 16;    // 64 MB
    float* partials = (float*)(base + 16384 + PF_BYTES);
    const size_t PART = (size_t)N_B * N_H * N_W;           // 4M floats
    const size_t need8 = 16384 + PF_BYTES + 8 * PART * 4;  // ~192 MB
    const size_t need2 = 16384 + PF_BYTES + 2 * PART * 4;  // ~96 MB

    fan_setup_kernel<<<4, 256, 0, stream>>>(angles, twr, twi, cs);
    fan_fft_filter4_kernel<<<4 * N_A, 256, 0, stream>>>(sino, filt, twr, twi,
                                                        pf4);
    if (ws_size >= need8) {
        fan_backproject_kernel<8><<<1024 * 8, 256, 0, stream>>>(pf4, cs,
                                                                partials);
        fan_reduce_kernel<8><<<(int)(PART / 4 / 256), 256, 0, stream>>>(
            (const float4*)partials, (float4*)out);
    } else if (ws_size >= need2) {
        fan_backproject_kernel<2><<<1024 * 2, 256, 0, stream>>>(pf4, cs,
                                                                partials);
        fan_reduce_kernel<2><<<(int)(PART / 4 / 256), 256, 0, stream>>>(
            (const float4*)partials, (float4*)out);
    } else {
        fan_backproject_kernel<1><<<1024, 256, 0, stream>>>(pf4, cs, out);
    }
}

// Round 14
// 513.317 us; speedup vs baseline: 2.3384x; 1.1167x over previous
//
#include <hip/hip_runtime.h>
#include <hip/hip_fp16.h>
#include <math.h>

#define N_B 16
#define N_A 1024
#define N_D 1024
#define N_H 512
#define N_W 512

typedef _Float16 half2t __attribute__((ext_vector_type(2)));

__device__ inline half2t h2cast(unsigned u) {
    union { unsigned u; half2t h; } cv; cv.u = u; return cv.h;
}

__device__ inline float fdot2f(half2t a, half2t b, float c) {
#if __has_builtin(__builtin_amdgcn_fdot2)
    return __builtin_amdgcn_fdot2(a, b, c, false);
#else
    asm("v_dot2_f32_f16 %0, %1, %2, %0" : "+v"(c) : "v"(a), "v"(b));
    return c;
#endif
}

__device__ inline half2t pack_h2(float lo, float hi) {
#if __has_builtin(__builtin_amdgcn_cvt_pkrtz)
    auto r = __builtin_amdgcn_cvt_pkrtz(lo, hi);
    union { decltype(r) a; half2t h; } cv; cv.a = r; return cv.h;
#else
    half2t r; r.x = (_Float16)lo; r.y = (_Float16)hi; return r;
#endif
}

__device__ inline unsigned pack_u(float lo, float hi) {
    union { half2t h; unsigned u; } cv; cv.h = pack_h2(lo, hi); return cv.u;
}

__device__ inline float med3f(float a, float lo, float hi) {
#if __has_builtin(__builtin_amdgcn_fmed3f)
    return __builtin_amdgcn_fmed3f(a, lo, hi);
#else
    return fminf(fmaxf(a, lo), hi);
#endif
}

// ---------------------------------------------------------------------------
__global__ void fan_setup_kernel(const float* __restrict__ angles,
                                 float* __restrict__ twr,
                                 float* __restrict__ twi,
                                 float2* __restrict__ cs) {
    int t = blockIdx.x * 256 + threadIdx.x;
    if (t < 512) {
        double ang = -2.0 * M_PI * (double)t / 1024.0;
        twr[t] = (float)cos(ang);
        twi[t] = (float)sin(ang);
    }
    if (t < 1024) {
        double b = (double)angles[t];
        cs[t] = make_float2((float)cos(b), (float)sin(b));
    }
}

// ---------------------------------------------------------------------------
// Per (32x32-tile, angle) window base. u is monotone along tile rows
// (d idx/dx = -960(750 s + y)/t^2, sign indep. of x) and columns
// (d idx/dy = 960(750 c + x)/t^2, sign indep. of y), so tile min = corner
// min. |grad idx| = 960 R / t^2 <= 3.38 bins/px (R = sqrt(t^2 + u'^2),
// |u'| <= 361, t >= 389) -> tile span <= 3.38*43.8 ~ 148 << 256-entry
// window. base = floor(min)-2, clamped to [0, 768].
// ---------------------------------------------------------------------------
__global__ __launch_bounds__(256) void fan_umin_kernel(
    const float2* __restrict__ cs, unsigned* __restrict__ utab) {
    const int t = blockIdx.x * 256 + threadIdx.x;  // 256 tiles * 1024 angles
    const int a = t & (N_A - 1);
    const int tile = t >> 10;
    const float2 p = cs[a];
    const float c = p.x, s = p.y;
    const float x0 = (float)((tile & 15) * 32) - 255.5f;
    const float x1 = x0 + 31.0f;
    const float y0 = (float)((tile >> 4) * 32) - 255.5f;
    const float y1 = y0 + 31.0f;
    float m = 1e30f;
#pragma unroll
    for (int i = 0; i < 4; ++i) {
        const float xx = (i & 1) ? x1 : x0;
        const float yy = (i & 2) ? y1 : y0;
        const float tt = 750.0f + xx * c + yy * s;
        const float idx = (960.0f * (yy * c - xx * s)) / tt + 511.5f;
        m = fminf(m, idx);
    }
    int base = (int)floorf(m) - 2;
    base = base < 0 ? 0 : (base > 768 ? 768 : base);
    utab[t] = (unsigned)base;
}

// ---------------------------------------------------------------------------
// FFT ramp filter: output [g][a][d], 16B entries = 4 batches' bilinear half2
// pair (f[d], f[d+1]).
// ---------------------------------------------------------------------------
__global__ __launch_bounds__(256) void fan_fft_filter4_kernel(
    const float* __restrict__ sino, const float* __restrict__ filt,
    const float* __restrict__ twr_g, const float* __restrict__ twi_g,
    uint4* __restrict__ pf4) {
    __shared__ float s_re0[1024], s_im0[1024];
    __shared__ float s_re1[1024], s_im1[1024];
    __shared__ float s_twr[512], s_twi[512];

    const int tid = threadIdx.x;
    const int a = blockIdx.x & (N_A - 1);
    const int g = blockIdx.x >> 10;

    {
        float2 t0 = ((const float2*)twr_g)[tid];
        s_twr[2 * tid] = t0.x; s_twr[2 * tid + 1] = t0.y;
        float2 t1 = ((const float2*)twi_g)[tid];
        s_twi[2 * tid] = t1.x; s_twi[2 * tid + 1] = t1.y;
    }
    {
        const size_t rowstride = (size_t)N_A * N_D;
        const float* rb = sino + (size_t)(4 * g) * rowstride + (size_t)a * N_D;
        ((float4*)s_re0)[tid] = ((const float4*)(rb + 0 * rowstride))[tid];
        ((float4*)s_im0)[tid] = ((const float4*)(rb + 1 * rowstride))[tid];
        ((float4*)s_re1)[tid] = ((const float4*)(rb + 2 * rowstride))[tid];
        ((float4*)s_im1)[tid] = ((const float4*)(rb + 3 * rowstride))[tid];
    }
    __syncthreads();

    for (int L = 9; L >= 0; --L) {
        const int half = 1 << L;
#pragma unroll
        for (int q = 0; q < 4; ++q) {
            float* re = (q < 2) ? s_re0 : s_re1;
            float* im = (q < 2) ? s_im0 : s_im1;
            const int bf = tid + ((q & 1) << 8);
            const int j = bf & (half - 1);
            const int blk = bf >> L;
            const int base = (blk << (L + 1)) + j;
            const int tw = j << (9 - L);
            const float wr = s_twr[tw], wi = s_twi[tw];
            const float ar = re[base], ai = im[base];
            const float br = re[base + half], bi = im[base + half];
            re[base] = ar + br;
            im[base] = ai + bi;
            const float dr = ar - br, di = ai - bi;
            re[base + half] = dr * wr - di * wi;
            im[base + half] = dr * wi + di * wr;
        }
        __syncthreads();
    }

#pragma unroll
    for (int q = 0; q < 4; ++q) {
        const int i = tid + (q << 8);
        const int ri = (int)(__brev((unsigned)i) >> 22);
        const float f = filt[ri];
        s_re0[i] *= f; s_im0[i] *= f;
        s_re1[i] *= f; s_im1[i] *= f;
    }
    __syncthreads();

    for (int L = 0; L <= 9; ++L) {
        const int half = 1 << L;
#pragma unroll
        for (int q = 0; q < 4; ++q) {
            float* re = (q < 2) ? s_re0 : s_re1;
            float* im = (q < 2) ? s_im0 : s_im1;
            const int bf = tid + ((q & 1) << 8);
            const int j = bf & (half - 1);
            const int blk = bf >> L;
            const int base = (blk << (L + 1)) + j;
            const int tw = j << (9 - L);
            const float wr = s_twr[tw], wi = -s_twi[tw];
            const float ar = re[base], ai = im[base];
            const float tr = re[base + half], ti = im[base + half];
            const float br = tr * wr - ti * wi;
            const float bi = tr * wi + ti * wr;
            re[base] = ar + br;
            im[base] = ai + bi;
            re[base + half] = ar - br;
            im[base + half] = ai - bi;
        }
        __syncthreads();
    }

    const float invN = 1.0f / 1024.0f;
    uint4* dst = pf4 + ((size_t)g * N_A + (size_t)a) * N_D;
#pragma unroll
    for (int q = 0; q < 4; ++q) {
        const int n = tid + (q << 8);
        const int n1 = (n < 1023) ? n + 1 : n;
        const float e = (n < 1023) ? 1.0f : 0.0f;
        uint4 v;
        v.x = pack_u(s_re0[n] * invN, s_re0[n1] * invN * e);
        v.y = pack_u(s_im0[n] * invN, s_im0[n1] * invN * e);
        v.z = pack_u(s_re1[n] * invN, s_re1[n1] * invN * e);
        v.w = pack_u(s_im1[n] * invN, s_im1[n1] * invN * e);
        dst[n] = v;
    }
}

// ---------------------------------------------------------------------------
// Backprojection, hybrid pipes, PLAIN C++ (compiler-managed waits):
// 32x32-pixel block (1024 thr). Groups 0,1 -> per-pixel TCP gathers.
// Groups 2,3 -> 256-entry LDS window staged coalesced (uint2 per lane),
// double-buffered, ONE __syncthreads per angle (sound with dbuf: a wave's
// write to buf[k&1] at iter k is after barrier k-1, which is after every
// wave's reads of that buffer at iter k-2). Window offset clamped to
// [0,255]; out-of-range pixels have weight 0 so the clamped read is benign.
// ---------------------------------------------------------------------------
template <int SPLIT>
__global__ __launch_bounds__(1024) void fan_backproject_kernel(
    const uint4* __restrict__ pf4, const float2* __restrict__ cs_g,
    const unsigned* __restrict__ utab, float* __restrict__ dst0) {
    constexpr int ACNT = N_A / SPLIT;
    __shared__ float2 lcs[ACNT];
    __shared__ unsigned s_ub[ACNT];
    __shared__ uint2 win[2][1024];  // 16 KB: [buf][g*512 + e*2 + h]
    const int tid = threadIdx.x;

    int part, tile;
    if (SPLIT == 4) {
        part = blockIdx.x & 3;   // round-robin: each XCD works one slice
        tile = blockIdx.x >> 2;
    } else {
        part = 0;
        tile = blockIdx.x;
    }
    const int abase = part * ACNT;

    // stage loop tables
    const unsigned* __restrict__ utrow = utab + (size_t)tile * N_A + abase;
    for (int i = tid; i < ACNT; i += 1024) {
        lcs[i] = cs_g[abase + i];
        s_ub[i] = utrow[i];
    }

    const int xi = (tile & 15) * 32 + (tid & 31);
    const int yi = (tile >> 4) * 32 + (tid >> 5);
    const float x = (float)xi - 255.5f;
    const float y = (float)yi - 255.5f;

    const uint4* __restrict__ g0 = pf4;                       // batches 0-3
    const uint4* __restrict__ g1 = pf4 + ((size_t)1 << 20);   // batches 4-7
    // staging: thread tid covers uint2 chunk tid of the 8KB window image:
    // g = tid>>9 (0 -> group2, 1 -> group3), e = (tid>>1)&255, h = tid&1
    const unsigned sg = (unsigned)tid >> 9;
    const unsigned se = ((unsigned)tid >> 1) & 255u;
    const unsigned sh = (unsigned)tid & 1u;
    const uint2* __restrict__ gsrc =
        (const uint2*)pf4 + ((size_t)(2 + sg) << 21);  // group base (uint2)

    float acc[N_B];
#pragma unroll
    for (int b = 0; b < N_B; ++b) acc[b] = 0.0f;

    __syncthreads();  // tables ready

    // prefetch window(0) into regs
    uint2 pre;
    {
        const unsigned e = min(s_ub[0] + se, 1023u);
        pre = gsrc[(((unsigned)abase) << 11) + e * 2u + sh];
    }

    for (int k = 0; k < ACNT; ++k) {
        // write window(k) to buf[k&1]; prefetch window(k+1)
        win[k & 1][tid] = pre;
        if (k + 1 < ACNT) {
            const unsigned e = min(s_ub[k + 1] + se, 1023u);
            pre = gsrc[(((unsigned)(abase + k + 1)) << 11) + e * 2u + sh];
        }
        __syncthreads();  // buf[k&1] visible; also fences buf reuse (dbuf)

        // geometry
        const float2 csp = lcs[k];
        const float c = csp.x, s = csp.y;
        const float t = fmaf(x, c, fmaf(y, s, 750.0f));
        const float r = __builtin_amdgcn_rcpf(t);
        const float num = fmaf(y, c, -(x * s));
        const float idx = fmaf(num * r, 960.0f, 511.5f);
        const float idxc = med3f(idx, 0.0f, 1023.0f);
        const float i0f = floorf(idxc);
        const float frac = idxc - i0f;
        const float wrr = 750.0f * r;
        float wd = wrr * wrr;
        wd = (idx == idxc) ? wd : 0.0f;
        const float w1 = wd * frac;
        const float w0 = wd - w1;
        const half2t wp = pack_h2(w0, w1);
        const int i0 = (int)i0f;
        const unsigned off = (((unsigned)(abase + k)) << 10) + (unsigned)i0;
        int oi = i0 - (int)s_ub[k];
        oi = oi < 0 ? 0 : (oi > 255 ? 255 : oi);  // clamp: w=0 cases only

        const uint4 v0 = g0[off];
        const uint4 v1 = g1[off];
        const uint4* wbuf = (const uint4*)(&win[k & 1][0]);
        const uint4 w2 = wbuf[(unsigned)oi];          // group2: e within 4KB
        const uint4 w3 = wbuf[256u + (unsigned)oi];   // group3

        acc[0] = fdot2f(h2cast(v0.x), wp, acc[0]);
        acc[1] = fdot2f(h2cast(v0.y), wp, acc[1]);
        acc[2] = fdot2f(h2cast(v0.z), wp, acc[2]);
        acc[3] = fdot2f(h2cast(v0.w), wp, acc[3]);
        acc[4] = fdot2f(h2cast(v1.x), wp, acc[4]);
        acc[5] = fdot2f(h2cast(v1.y), wp, acc[5]);
        acc[6] = fdot2f(h2cast(v1.z), wp, acc[6]);
        acc[7] = fdot2f(h2cast(v1.w), wp, acc[7]);
        acc[8] = fdot2f(h2cast(w2.x), wp, acc[8]);
        acc[9] = fdot2f(h2cast(w2.y), wp, acc[9]);
        acc[10] = fdot2f(h2cast(w2.z), wp, acc[10]);
        acc[11] = fdot2f(h2cast(w2.w), wp, acc[11]);
        acc[12] = fdot2f(h2cast(w3.x), wp, acc[12]);
        acc[13] = fdot2f(h2cast(w3.y), wp, acc[13]);
        acc[14] = fdot2f(h2cast(w3.z), wp, acc[14]);
        acc[15] = fdot2f(h2cast(w3.w), wp, acc[15]);
    }

    const float scale = 3.14159265358979323846f / 1024.0f;  // pi / A
    float* dst = dst0 + (size_t)part * ((size_t)N_B * N_H * N_W);
    const size_t pix = (size_t)yi * N_W + (size_t)xi;
#pragma unroll
    for (int b = 0; b < N_B; ++b) {
        dst[(size_t)b * (N_H * N_W) + pix] = acc[b] * scale;
    }
}

// ---------------------------------------------------------------------------
template <int NS>
__global__ __launch_bounds__(256) void fan_reduce_kernel(
    const float4* __restrict__ p, float4* __restrict__ o) {
    const int i = blockIdx.x * 256 + threadIdx.x;
    const size_t stride = (size_t)N_B * N_H * N_W / 4;
    float4 v = p[i];
#pragma unroll
    for (int k = 1; k < NS; ++k) {
        const float4 w = p[(size_t)k * stride + i];
        v.x += w.x; v.y += w.y; v.z += w.z; v.w += w.w;
    }
    o[i] = v;
}

// ---------------------------------------------------------------------------
extern "C" void kernel_launch(void* const* d_in, const int* in_sizes, int n_in,
                              void* d_out, int out_size, void* d_ws, size_t ws_size,
                              hipStream_t stream) {
    const float* sino = (const float*)d_in[0];    // [16, 1024, 1024] f32
    const float* filt = (const float*)d_in[1];    // [1024] f32
    const float* angles = (const float*)d_in[2];  // [1024] f32
    float* out = (float*)d_out;                   // [16, 512, 512] f32

    float* twr = (float*)d_ws;
    float* twi = twr + 512;
    float2* cs = (float2*)(twi + 512);
    char* base = (char*)d_ws;
    unsigned* utab = (unsigned*)(base + 16384);            // 1 MB
    uint4* pf4 = (uint4*)(base + 16384 + (1 << 20));
    const size_t PF_BYTES = (size_t)4 * N_A * N_D * 16;    // 64 MB
    float* partials = (float*)(base + 16384 + (1 << 20) + PF_BYTES);
    const size_t PART = (size_t)N_B * N_H * N_W;           // 4M floats
    const size_t need4 = 16384 + (1 << 20) + PF_BYTES + 4 * PART * 4;
    const size_t need1 = 16384 + (1 << 20) + PF_BYTES;

    fan_setup_kernel<<<4, 256, 0, stream>>>(angles, twr, twi, cs);
    fan_umin_kernel<<<1024, 256, 0, stream>>>(cs, utab);
    fan_fft_filter4_kernel<<<4 * N_A, 256, 0, stream>>>(sino, filt, twr, twi,
                                                        pf4);
    if (ws_size >= need4) {
        fan_backproject_kernel<4><<<256 * 4, 1024, 0, stream>>>(pf4, cs, utab,
                                                                partials);
        fan_reduce_kernel<4><<<(int)(PART / 4 / 256), 256, 0, stream>>>(
            (const float4*)partials, (float4*)out);
    } else if (ws_size >= need1) {
        fan_backproject_kernel<1><<<256, 1024, 0, stream>>>(pf4, cs, utab,
                                                            out);
    }
}